// Round 1
// baseline (331.190 us; speedup 1.0000x reference)
//
#include <hip/hip_runtime.h>

// Fused ResidualTokenAdapter: LN -> down(1024->64) -> GELU(erf) -> up(64->1024) -> +x
// x: (8,4096,1024) fp32. One block (256 thr, 4 waves) handles RT=16 rows.

#define HDIM 1024
#define BDIM 64
#define RT   16
#define XPAD 1032   // row stride (shorts) for x/xn LDS tiles: 2064 B = 16B-multiple, 4-dword bank skew
#define GPAD 72     // row stride (shorts) for g tile: 144 B = 16B-multiple

using s16x8 = __attribute__((ext_vector_type(8))) short;
using s16x4 = __attribute__((ext_vector_type(4))) short;
using f32x4 = __attribute__((ext_vector_type(4))) float;

__device__ __forceinline__ short f2bf(float f) {
  unsigned u = __builtin_bit_cast(unsigned, f);
  u += 0x7fffu + ((u >> 16) & 1u);          // round-to-nearest-even
  return (short)(u >> 16);
}
__device__ __forceinline__ float bf2f(short s) {
  unsigned u = ((unsigned)(unsigned short)s) << 16;
  return __builtin_bit_cast(float, u);
}

extern "C" __global__ __launch_bounds__(256, 2)
void adapter_fused(const float* __restrict__ x,
                   const float* __restrict__ nw, const float* __restrict__ nb,
                   const float* __restrict__ dw, const float* __restrict__ db,
                   const float* __restrict__ uw, const float* __restrict__ ub,
                   float* __restrict__ out)
{
  __shared__ __align__(16) short xbf[RT][XPAD];   // x rounded to bf16 (residual source)
  __shared__ __align__(16) short xnbf[RT][XPAD];  // normalized x, bf16 (down-GEMM A)
  __shared__ __align__(16) short gbf[RT][GPAD];   // gelu(h), bf16 (up-GEMM A)
  __shared__ float wln[HDIM];
  __shared__ float bln[HDIM];

  const int t  = threadIdx.x;
  const int rb = blockIdx.x * RT;

  // stage LN gamma/beta (256 threads x 4 floats = 1024)
  {
    f32x4 w4 = ((const f32x4*)nw)[t];
    f32x4 b4 = ((const f32x4*)nb)[t];
    *(f32x4*)&wln[t * 4] = w4;
    *(f32x4*)&bln[t * 4] = b4;
  }

  // ---- phase 1: load x (coalesced float4), row stats, store x as bf16 ----
  const int r  = t >> 4;    // row 0..15 (16 threads per row)
  const int cl = t & 15;
  const float* xrow = x + (size_t)(rb + r) * HDIM;
  float sum = 0.f, ssq = 0.f;
#pragma unroll
  for (int i = 0; i < 16; ++i) {
    int j4 = i * 16 + cl;                       // float4 index within row
    f32x4 v = ((const f32x4*)xrow)[j4];
    s16x4 s;
#pragma unroll
    for (int k = 0; k < 4; ++k) { float f = v[k]; sum += f; ssq += f * f; s[k] = f2bf(f); }
    *(s16x4*)&xbf[r][j4 * 4] = s;
  }
#pragma unroll
  for (int m = 1; m < 16; m <<= 1) {
    sum += __shfl_xor(sum, m, 64);
    ssq += __shfl_xor(ssq, m, 64);
  }
  const float mu = sum * (1.0f / HDIM);
  const float var = ssq * (1.0f / HDIM) - mu * mu;
  const float rs = rsqrtf(var + 1e-5f);
  __syncthreads();

  // ---- phase 2: normalize -> xnbf (each thread re-reads its own stored chunk) ----
#pragma unroll
  for (int i = 0; i < 16; ++i) {
    int j = (i * 16 + cl) * 4;
    s16x4 s = *(const s16x4*)&xbf[r][j];
    s16x4 o;
#pragma unroll
    for (int k = 0; k < 4; ++k) {
      float xf = bf2f(s[k]);
      o[k] = f2bf((xf - mu) * rs * wln[j + k] + bln[j + k]);
    }
    *(s16x4*)&xnbf[r][j] = o;
  }
  __syncthreads();

  // ---- phase 3: down GEMM  D[16x64] = xn[16x1024] * dw^T ----
  // MFMA 16x16x32: A[m=lane&15][k=(lane>>4)*8+j], B[k][n=lane&15], D[m=(lane>>4)*4+i][n=lane&15]
  const int wv   = t >> 6;     // wave 0..3 -> N-tile of down GEMM
  const int lane = t & 63;
  const int q    = lane >> 4;
  const int c    = lane & 15;
  f32x4 acc = {0.f, 0.f, 0.f, 0.f};
  const float* dwrow = dw + (size_t)(wv * 16 + c) * HDIM;   // B[k][n]=dw[n][k], n = wv*16+c
#pragma unroll 4
  for (int ks = 0; ks < 32; ++ks) {
    int k0 = ks * 32 + q * 8;
    s16x8 a = *(const s16x8*)&xnbf[c][k0];
    f32x4 b0 = *(const f32x4*)(dwrow + k0);
    f32x4 b1 = *(const f32x4*)(dwrow + k0 + 4);
    s16x8 b;
#pragma unroll
    for (int k = 0; k < 4; ++k) { b[k] = f2bf(b0[k]); b[k + 4] = f2bf(b1[k]); }
    acc = __builtin_amdgcn_mfma_f32_16x16x32_bf16(a, b, acc, 0, 0, 0);
  }

  // ---- phase 4: +bias, exact GELU, store g as bf16 (A-layout source for up GEMM) ----
  {
    float dbv = db[wv * 16 + c];
#pragma unroll
    for (int i = 0; i < 4; ++i) {
      float hv = acc[i] + dbv;
      float g  = 0.5f * hv * (1.0f + erff(hv * 0.70710678118654752f));
      gbf[q * 4 + i][wv * 16 + c] = f2bf(g);
    }
  }
  __syncthreads();

  // ---- phase 5: up GEMM D[16x1024] = g[16x64] * uw^T, +bias +residual, store ----
  s16x8 a0 = *(const s16x8*)&gbf[c][q * 8];        // k = 0..31 slice
  s16x8 a1 = *(const s16x8*)&gbf[c][32 + q * 8];   // k = 32..63 slice
#pragma unroll 2
  for (int nt = 0; nt < 16; ++nt) {
    int ncol = wv * 256 + nt * 16 + c;             // this wave owns cols [wv*256, wv*256+256)
    const float* uwrow = uw + (size_t)ncol * BDIM; // B[k][n]=uw[n][k], contiguous in k
    f32x4 u0 = *(const f32x4*)(uwrow + q * 8);
    f32x4 u1 = *(const f32x4*)(uwrow + q * 8 + 4);
    f32x4 u2 = *(const f32x4*)(uwrow + 32 + q * 8);
    f32x4 u3 = *(const f32x4*)(uwrow + 32 + q * 8 + 4);
    s16x8 b0, b1;
#pragma unroll
    for (int k = 0; k < 4; ++k) {
      b0[k] = f2bf(u0[k]); b0[k + 4] = f2bf(u1[k]);
      b1[k] = f2bf(u2[k]); b1[k + 4] = f2bf(u3[k]);
    }
    f32x4 o4 = {0.f, 0.f, 0.f, 0.f};
    o4 = __builtin_amdgcn_mfma_f32_16x16x32_bf16(a0, b0, o4, 0, 0, 0);
    o4 = __builtin_amdgcn_mfma_f32_16x16x32_bf16(a1, b1, o4, 0, 0, 0);
    float ubv = ub[ncol];
#pragma unroll
    for (int i = 0; i < 4; ++i) {
      int row = q * 4 + i;
      float xres = bf2f(xbf[row][ncol]);
      out[(size_t)(rb + row) * HDIM + ncol] = o4[i] + ubv + xres;
    }
  }
}

extern "C" void kernel_launch(void* const* d_in, const int* in_sizes, int n_in,
                              void* d_out, int out_size, void* d_ws, size_t ws_size,
                              hipStream_t stream) {
  const float* x  = (const float*)d_in[0];
  const float* nw = (const float*)d_in[1];
  const float* nb = (const float*)d_in[2];
  const float* dw = (const float*)d_in[3];
  const float* db = (const float*)d_in[4];
  const float* uw = (const float*)d_in[5];
  const float* ub = (const float*)d_in[6];
  float* out = (float*)d_out;

  const int rows = in_sizes[0] / HDIM;       // 8*4096 = 32768
  const int grid = rows / RT;                // 2048 blocks
  adapter_fused<<<grid, 256, 0, stream>>>(x, nw, nb, dw, db, uw, ub, out);
}

// Round 2
// 290.124 us; speedup vs baseline: 1.1415x; 1.1415x over previous
//
#include <hip/hip_runtime.h>

// Fused ResidualTokenAdapter: LN -> down(1024->64) -> GELU(erf) -> up(64->1024) -> +x
// x: (8,4096,1024) fp32. Block = 512 thr (8 waves) handles RT=32 rows.
// Weights pre-converted to bf16 in d_ws by prep kernel (runs every call).

#define HDIM 1024
#define BDIM 64
#define RT   32
#define XPAD 1032   // row stride (shorts): 2064 B, 16B-aligned, 4-dword bank skew -> 2-way (free)
#define GPAD 72     // row stride (shorts) for g tile

using s16x8 = __attribute__((ext_vector_type(8))) short;
using s16x4 = __attribute__((ext_vector_type(4))) short;
using f32x4 = __attribute__((ext_vector_type(4))) float;
using f32x2 = __attribute__((ext_vector_type(2))) float;

__device__ __forceinline__ short f2bf(float f) {
  unsigned u = __builtin_bit_cast(unsigned, f);
  u += 0x7fffu + ((u >> 16) & 1u);          // round-to-nearest-even
  return (short)(u >> 16);
}
__device__ __forceinline__ float bf2f(short s) {
  unsigned u = ((unsigned)(unsigned short)s) << 16;
  return __builtin_bit_cast(float, u);
}

// ---- prep: fp32 weights -> bf16 in ws. dwb = ws[0:65536), uwb = ws[65536:131072)
extern "C" __global__ void prep_weights(const float* __restrict__ dw,
                                        const float* __restrict__ uw,
                                        short* __restrict__ wsbf) {
  int tid = blockIdx.x * 256 + threadIdx.x;          // 0..16383, whole waves per side
  const float* src = (tid < 8192) ? dw : uw;
  int off = (tid < 8192) ? tid * 8 : (tid - 8192) * 8;
  f32x4 v0 = *(const f32x4*)(src + off);
  f32x4 v1 = *(const f32x4*)(src + off + 4);
  s16x8 o;
#pragma unroll
  for (int k = 0; k < 4; ++k) { o[k] = f2bf(v0[k]); o[k + 4] = f2bf(v1[k]); }
  *(s16x8*)(wsbf + tid * 8) = o;                     // dest offset tid*8 works for both halves
}

extern "C" __global__ __launch_bounds__(512, 4)
void adapter_fused(const float* __restrict__ x,
                   const float* __restrict__ nw, const float* __restrict__ nb,
                   const float* __restrict__ db, const float* __restrict__ ub,
                   const short* __restrict__ dwb, const short* __restrict__ uwb,
                   float* __restrict__ out)
{
  __shared__ __align__(16) short xnbf[RT][XPAD];  // raw x bf16, then normalized in place
  __shared__ __align__(16) short gbf[RT][GPAD];   // gelu(h) bf16 (up-GEMM A source)
  __shared__ float wln[HDIM];
  __shared__ float bln[HDIM];

  const int t  = threadIdx.x;
  const int rb = blockIdx.x * RT;

  // stage LN gamma/beta (512 threads x 2 floats)
  {
    f32x2 w2 = ((const f32x2*)nw)[t];
    f32x2 b2 = ((const f32x2*)nb)[t];
    *(f32x2*)&wln[t * 2] = w2;
    *(f32x2*)&bln[t * 2] = b2;
  }

  // ---- phase 1: load x (coalesced float4), row stats, store raw bf16 ----
  const int r  = t >> 4;    // row 0..31 (16 threads per row)
  const int cl = t & 15;
  const float* xrow = x + (size_t)(rb + r) * HDIM;
  float sum = 0.f, ssq = 0.f;
#pragma unroll 8
  for (int i = 0; i < 16; ++i) {
    int j4 = i * 16 + cl;                       // float4 index within row
    f32x4 v = ((const f32x4*)xrow)[j4];
    s16x4 s;
#pragma unroll
    for (int k = 0; k < 4; ++k) { float f = v[k]; sum += f; ssq += f * f; s[k] = f2bf(f); }
    *(s16x4*)&xnbf[r][j4 * 4] = s;
  }
#pragma unroll
  for (int m = 1; m < 16; m <<= 1) {
    sum += __shfl_xor(sum, m);
    ssq += __shfl_xor(ssq, m);
  }
  const float mu  = sum * (1.0f / HDIM);
  const float var = ssq * (1.0f / HDIM) - mu * mu;
  const float rs  = rsqrtf(var + 1e-5f);

  // ---- phase 2: normalize in place (thread's own chunk, no cross-thread hazard) ----
#pragma unroll
  for (int i = 0; i < 16; ++i) {
    int j = (i * 16 + cl) * 4;
    s16x4 s = *(const s16x4*)&xnbf[r][j];
    s16x4 o;
#pragma unroll
    for (int k = 0; k < 4; ++k) {
      float xf = bf2f(s[k]);
      o[k] = f2bf((xf - mu) * rs * wln[j + k] + bln[j + k]);
    }
    *(s16x4*)&xnbf[r][j] = o;
  }
  __syncthreads();

  // ---- phase 3: down GEMM  D[32x64] = xn[32x1024] * dw^T ----
  // MFMA 16x16x32: A[m=lane&15][k=q*8+j], B[k][n=lane&15], D[m=q*4+i][n=lane&15]
  const int w    = t >> 6;     // wave 0..7
  const int lane = t & 63;
  const int q    = lane >> 4;
  const int c    = lane & 15;
  const int rt   = w & 1;      // row-tile 0..1
  const int ct   = w >> 1;     // col-tile 0..3 (down) / col-quarter (up)
  f32x4 acc = {0.f, 0.f, 0.f, 0.f};
  const short* dwrow = dwb + (size_t)(ct * 16 + c) * HDIM;   // B[k][n]=dw[n][k]
#pragma unroll 4
  for (int ks = 0; ks < 32; ++ks) {
    int k0 = ks * 32 + q * 8;
    s16x8 a = *(const s16x8*)&xnbf[rt * 16 + c][k0];
    s16x8 b = *(const s16x8*)(dwrow + k0);
    acc = __builtin_amdgcn_mfma_f32_16x16x32_bf16(a, b, acc, 0, 0, 0);
  }

  // ---- phase 4: +bias, exact GELU, store g bf16 ----
  {
    float dbv = db[ct * 16 + c];
#pragma unroll
    for (int i = 0; i < 4; ++i) {
      float hv = acc[i] + dbv;
      float g  = 0.5f * hv * (1.0f + erff(hv * 0.70710678118654752f));
      gbf[rt * 16 + q * 4 + i][ct * 16 + c] = f2bf(g);
    }
  }
  __syncthreads();

  // ---- phase 5: up GEMM D[32x1024] = g[32x64] * uw^T, +bias +residual(fp32 x), store ----
  s16x8 a0 = *(const s16x8*)&gbf[rt * 16 + c][q * 8];        // k = 0..31
  s16x8 a1 = *(const s16x8*)&gbf[rt * 16 + c][32 + q * 8];   // k = 32..63
  const float* xbase = x   + (size_t)(rb + rt * 16) * HDIM;
  float*       obase = out + (size_t)(rb + rt * 16) * HDIM;
#pragma unroll 2
  for (int nt = 0; nt < 16; ++nt) {
    int ncol = ct * 256 + nt * 16 + c;             // wave owns cols [ct*256, ct*256+256)
    const short* uwrow = uwb + (size_t)ncol * BDIM;
    s16x8 b0 = *(const s16x8*)(uwrow + q * 8);
    s16x8 b1 = *(const s16x8*)(uwrow + 32 + q * 8);
    f32x4 o4 = {0.f, 0.f, 0.f, 0.f};
    o4 = __builtin_amdgcn_mfma_f32_16x16x32_bf16(a0, b0, o4, 0, 0, 0);
    o4 = __builtin_amdgcn_mfma_f32_16x16x32_bf16(a1, b1, o4, 0, 0, 0);
    float ubv = ub[ncol];
#pragma unroll
    for (int i = 0; i < 4; ++i) {
      int ro = (q * 4 + i) * HDIM + ncol;
      obase[ro] = o4[i] + ubv + xbase[ro];         // residual from fp32 x (L2-resident)
    }
  }
}

extern "C" void kernel_launch(void* const* d_in, const int* in_sizes, int n_in,
                              void* d_out, int out_size, void* d_ws, size_t ws_size,
                              hipStream_t stream) {
  const float* x  = (const float*)d_in[0];
  const float* nw = (const float*)d_in[1];
  const float* nb = (const float*)d_in[2];
  const float* dw = (const float*)d_in[3];
  const float* db = (const float*)d_in[4];
  const float* uw = (const float*)d_in[5];
  const float* ub = (const float*)d_in[6];
  float* out = (float*)d_out;

  short* wsbf = (short*)d_ws;                 // 131072 shorts = 256 KB
  prep_weights<<<64, 256, 0, stream>>>(dw, uw, wsbf);

  const int rows = in_sizes[0] / HDIM;        // 32768
  const int grid = rows / RT;                 // 1024 blocks
  adapter_fused<<<grid, 512, 0, stream>>>(x, nw, nb, db, ub,
                                          wsbf, wsbf + 65536, out);
}